// Round 1
// 5266.203 us; speedup vs baseline: 1.1049x; 1.1049x over previous
//
#include <hip/hip_runtime.h>
#include <hip/hip_bf16.h>

#define SEQ   1024
#define BATCH 64
#define INDIM 512
#define HID   1024

typedef __attribute__((ext_vector_type(8))) short bf16x8;
typedef __attribute__((ext_vector_type(4))) float f32x4;
typedef __attribute__((ext_vector_type(4))) int   i32x4;

// fp32 -> bf16 round-to-nearest-even
static __device__ __forceinline__ short f2bf(float f) {
    union { float f; unsigned u; } v; v.f = f;
    unsigned u = v.u;
    unsigned r = u + 0x7fffu + ((u >> 16) & 1u);
    return (short)(r >> 16);
}

// 16B device-coherent load: bypass L1 + XCD L2, read at the MALL coherence point.
static __device__ __forceinline__ i32x4 load16_coherent(const void* p) {
    i32x4 r;
    asm volatile("global_load_dwordx4 %0, %1, off sc0 sc1" : "=v"(r) : "v"(p) : "memory");
    return r;
}

// Division-free tanh: tanh(x) = (e^{2x}-1)/(e^{2x}+1) via v_exp_f32 + v_rcp_f32.
// Clamp +-9 avoids inf*0=NaN at exp2 overflow; |err| ~1e-6, far below the bf16
// h quantization (0.4% rel) that dominates absmax.
static __device__ __forceinline__ float fast_tanh(float x) {
    x = fminf(9.0f, fmaxf(-9.0f, x));
    float e = __builtin_amdgcn_exp2f(2.8853900817779268f * x);   // e^{2x}
    return (e - 1.0f) * __builtin_amdgcn_rcpf(e + 1.0f);
}

__global__ __launch_bounds__(256) void cvt_kernel(const float* __restrict__ src,
                                                  short* __restrict__ dst, int n) {
    int i = blockIdx.x * blockDim.x + threadIdx.x;
    int stride = gridDim.x * blockDim.x;
    for (; i < n; i += stride) dst[i] = f2bf(src[i]);
}

// Phase A: xp[m,n] = sum_k x[m,k]*Wih[n,k] + b_ih[n] + b_hh[n], written into d_out.
// Grid is 1D (16384) with an XCD-chunked mapping: the 16 n-blocks sharing one
// 64-row A panel all satisfy id%8 == p%8 (same XCD under round-robin dispatch)
// within a ~128-id window, so the 128KB fp32 A panel is fetched from HBM once
// and served from that XCD's L2 for the other 15 blocks. Previous (16,1024)
// grid spread each panel across all 8 XCDs -> ~8x A refetch, HBM-bound.
__global__ __launch_bounds__(256) void proj_kernel(
    const float* __restrict__ x,      // [65536, 512] fp32
    const short* __restrict__ wih,    // [1024, 512] bf16
    const float* __restrict__ b_ih,
    const float* __restrict__ b_hh,
    float* __restrict__ out)          // [65536, 1024] fp32
{
    const int tid  = threadIdx.x;
    const int lane = tid & 63;
    const int w    = tid >> 6;
    const int wm   = w & 1, wn = w >> 1;
    const int l15  = lane & 15;
    const int quad = lane >> 4;

    const int id  = blockIdx.x;
    const int xcd = id & 7;
    const int q   = id >> 3;
    const int n   = q & 15;          // col panel 0..15
    const int p   = (q >> 4) * 8 + xcd;  // row panel 0..1023

    const int bm = p * 64 + wm * 32;
    const int bn = n * 64 + wn * 32;

    f32x4 acc[2][2] = {};

    for (int kk = 0; kk < INDIM; kk += 32) {
        const int kbase = kk + quad * 8;
        bf16x8 a[2], b[2];
#pragma unroll
        for (int mi = 0; mi < 2; ++mi) {
            const float* ap = x + (size_t)(bm + mi * 16 + l15) * INDIM + kbase;
            float4 lo = *reinterpret_cast<const float4*>(ap);
            float4 hi = *reinterpret_cast<const float4*>(ap + 4);
            bf16x8 af;
            af[0] = f2bf(lo.x); af[1] = f2bf(lo.y); af[2] = f2bf(lo.z); af[3] = f2bf(lo.w);
            af[4] = f2bf(hi.x); af[5] = f2bf(hi.y); af[6] = f2bf(hi.z); af[7] = f2bf(hi.w);
            a[mi] = af;
        }
#pragma unroll
        for (int ni = 0; ni < 2; ++ni)
            b[ni] = *reinterpret_cast<const bf16x8*>(wih + (size_t)(bn + ni * 16 + l15) * INDIM + kbase);
#pragma unroll
        for (int mi = 0; mi < 2; ++mi)
#pragma unroll
            for (int ni = 0; ni < 2; ++ni)
                acc[mi][ni] = __builtin_amdgcn_mfma_f32_16x16x32_bf16(a[mi], b[ni], acc[mi][ni], 0, 0, 0);
    }

#pragma unroll
    for (int mi = 0; mi < 2; ++mi) {
#pragma unroll
        for (int ni = 0; ni < 2; ++ni) {
            const int col = bn + ni * 16 + l15;
            const float bias = b_ih[col] + b_hh[col];
#pragma unroll
            for (int reg = 0; reg < 4; ++reg) {
                const int row = bm + mi * 16 + quad * 4 + reg;
                out[(size_t)row * HID + col] = acc[mi][ni][reg] + bias;
            }
        }
    }
}

// Phase B: cooperative scan. 64 blocks = 4 groups x 16 blocks.
// Group g owns batches [16g,16g+16); block r in group owns cols [64r,64r+64).
// W_hh slice (64 cols x 1024 k, bf16) lives in VGPR/AGPR for the whole kernel.
//
// Sync protocol (this round): distributed per-block step flags instead of a
// central counter. Producer: sc1 h stores -> __syncthreads (per-thread vmcnt0:
// stores >= L2) -> tid0 fence(release,agent) (buffer_wbl2 sc1: L2 write queue
// -> MALL, closes the store->flag visibility race) -> relaxed sc1 flag store
// flag[r] = t+1. Consumer: wave w needs only K [256w,256w+256) = producers
// 4w..4w+3, so it spin-polls ONE sc0sc1 dwordx4 of those 4 flags >= t, then
// issues its h loads. Removes: counter-add RT, tid0 central poll + barrier
// broadcast, acquire buffer_inv (all cross-block reads are sc0sc1 anyway),
// one __syncthreads; shrinks per-step convergence from 16 producers to 4.
// Flag monotonicity makes the double-buffer hazard argument identical to the
// counter version (block's h_{t+1} stores happen-after all 16 producers'
// h_{t-1} reads, via flag(t) observation at the LDS-reduce barrier).
__global__ __launch_bounds__(256) void rnn_scan_kernel(
    float* __restrict__ out,              // [SEQ,BATCH,HID]: holds xp, overwritten with h_t
    const short* __restrict__ whh,        // [1024,1024] bf16
    short* __restrict__ hb0,              // [BATCH,HID] bf16 (zeroed = h0)
    short* __restrict__ hb1,              // [BATCH,HID] bf16
    unsigned int* __restrict__ flags)     // 4 groups x 16 flags, 256B apart, zeroed
{
    const int tid  = threadIdx.x;
    const int lane = tid & 63;
    const int w    = tid >> 6;
    const int l15  = lane & 15;
    const int quad = lane >> 4;

    const int gid = blockIdx.x;   // 0..63
    const int g   = gid >> 4;     // group 0..3
    const int r   = gid & 15;     // col-block 0..15
    const int b0  = g * 16;       // first batch of group
    const int n0  = r * 64;       // first hidden col of block

    // Preload W_hh fragments (loop-invariant): n-tile nt covers cols n0+16nt+l15,
    // wave w covers k in [256w, 256w+256).
    bf16x8 wfrag[4][8];
#pragma unroll
    for (int nt = 0; nt < 4; ++nt)
#pragma unroll
        for (int ks = 0; ks < 8; ++ks) {
            const int k = 256 * w + ks * 32 + quad * 8;
            wfrag[nt][ks] = *reinterpret_cast<const bf16x8*>(
                whh + (size_t)(n0 + nt * 16 + l15) * HID + k);
        }

    __shared__ float red[4 * 1024];

    short* hbufs[2] = { hb0, hb1 };
    unsigned int* gflags = flags + g * 64;          // 256B stride per group
    const unsigned int* wflag = gflags + w * 4;     // this wave's 4 producers (16B)

    const int m  = tid >> 4;        // batch row within group
    const int c0 = (tid & 15) * 4;  // 4 consecutive cols per thread in epilogue

    for (int t = 0; t < SEQ; ++t) {
        const short* hc = hbufs[t & 1];
        short*       hn = hbufs[(t + 1) & 1];

        // Block-local xp prefetch (independent of the handshake).
        const size_t oidx = (size_t)t * (BATCH * HID) + (size_t)(b0 + m) * HID + n0 + c0;
        float4 xp = *reinterpret_cast<const float4*>(out + oidx);

        // Per-wave readiness: wait until our 4 K-quarter producers published h_t.
        // Flag visible at MALL => producer's wbl2 done => h data at MALL; the
        // poll retires (vmcnt0) before the h loads issue, so no acquire needed.
        if (t != 0) {
            const unsigned tgt = (unsigned)t;
            for (;;) {
                i32x4 f;
                asm volatile("global_load_dwordx4 %0, %1, off sc0 sc1\n\ts_waitcnt vmcnt(0)"
                             : "=v"(f) : "v"(wflag) : "memory");
                if ((unsigned)f[0] >= tgt && (unsigned)f[1] >= tgt &&
                    (unsigned)f[2] >= tgt && (unsigned)f[3] >= tgt) break;
            }
        }

        // Coherent h loads: row b0+l15, wave-w K-quarter (8 x 16B, pipelined).
        i32x4 araw[8];
        const short* abase = hc + (size_t)(b0 + l15) * HID + 256 * w + quad * 8;
#pragma unroll
        for (int ks = 0; ks < 8; ++ks)
            araw[ks] = load16_coherent(abase + ks * 32);

        f32x4 acc[4] = {};
        // Split wait: start MFMA on the first 4 returns while 4..7 are in flight.
        asm volatile("s_waitcnt vmcnt(4)"
            : "+v"(araw[0]), "+v"(araw[1]), "+v"(araw[2]), "+v"(araw[3]) :: "memory");
#pragma unroll
        for (int ks = 0; ks < 4; ++ks) {
            bf16x8 a = __builtin_bit_cast(bf16x8, araw[ks]);
#pragma unroll
            for (int nt = 0; nt < 4; ++nt)
                acc[nt] = __builtin_amdgcn_mfma_f32_16x16x32_bf16(a, wfrag[nt][ks], acc[nt], 0, 0, 0);
        }
        asm volatile("s_waitcnt vmcnt(0)"
            : "+v"(araw[4]), "+v"(araw[5]), "+v"(araw[6]), "+v"(araw[7]) :: "memory");
#pragma unroll
        for (int ks = 4; ks < 8; ++ks) {
            bf16x8 a = __builtin_bit_cast(bf16x8, araw[ks]);
#pragma unroll
            for (int nt = 0; nt < 4; ++nt)
                acc[nt] = __builtin_amdgcn_mfma_f32_16x16x32_bf16(a, wfrag[nt][ks], acc[nt], 0, 0, 0);
        }

        // Cross-wave K-reduction via LDS. C/D layout: col=l15, row=quad*4+reg.
#pragma unroll
        for (int nt = 0; nt < 4; ++nt)
#pragma unroll
            for (int reg = 0; reg < 4; ++reg)
                red[w * 1024 + (quad * 4 + reg) * 64 + nt * 16 + l15] = acc[nt][reg];
        __syncthreads();

        {
            // ds_read_b128 per partial (c0 is 16B-aligned).
            f32x4 s = *reinterpret_cast<const f32x4*>(&red[0 * 1024 + m * 64 + c0]);
#pragma unroll
            for (int wk = 1; wk < 4; ++wk) {
                f32x4 sp = *reinterpret_cast<const f32x4*>(&red[wk * 1024 + m * 64 + c0]);
                s[0] += sp[0]; s[1] += sp[1]; s[2] += sp[2]; s[3] += sp[3];
            }

            float v0 = fast_tanh(s[0] + xp.x);
            float v1 = fast_tanh(s[1] + xp.y);
            float v2 = fast_tanh(s[2] + xp.z);
            float v3 = fast_tanh(s[3] + xp.w);
            *reinterpret_cast<float4*>(out + oidx) = make_float4(v0, v1, v2, v3);

            // Device-scope h store: 4 bf16 packed into one 8B relaxed atomic (sc1).
            unsigned lo = (unsigned)(unsigned short)f2bf(v0) | ((unsigned)(unsigned short)f2bf(v1) << 16);
            unsigned hi = (unsigned)(unsigned short)f2bf(v2) | ((unsigned)(unsigned short)f2bf(v3) << 16);
            unsigned long long pk = (unsigned long long)lo | ((unsigned long long)hi << 32);
            __hip_atomic_store(
                reinterpret_cast<unsigned long long*>(hn + (size_t)(b0 + m) * HID + n0 + c0),
                pk, __ATOMIC_RELAXED, __HIP_MEMORY_SCOPE_AGENT);
        }

        // __syncthreads drains every thread's stores (vmcnt0) to at least L2;
        // the release fence then drains the XCD L2 write path to the MALL before
        // the flag becomes visible. No trailing barrier: waves go straight to
        // the next iteration's poll; wave 0 absorbs the wbl2 latency, which is
        // symmetric across blocks (its producers' flags are equally delayed).
        __syncthreads();
        if (tid == 0) {
            __builtin_amdgcn_fence(__ATOMIC_RELEASE, "agent");
            __hip_atomic_store(&gflags[r], (unsigned)(t + 1),
                               __ATOMIC_RELAXED, __HIP_MEMORY_SCOPE_AGENT);
        }
    }
}

extern "C" void kernel_launch(void* const* d_in, const int* in_sizes, int n_in,
                              void* d_out, int out_size, void* d_ws, size_t ws_size,
                              hipStream_t stream) {
    const float* x    = (const float*)d_in[0];   // [1024,64,512]
    const float* wih  = (const float*)d_in[1];   // [1024,512]
    const float* whh  = (const float*)d_in[2];   // [1024,1024]
    const float* b_ih = (const float*)d_in[3];   // [1024]
    const float* b_hh = (const float*)d_in[4];   // [1024]
    float* out = (float*)d_out;                  // [1024,64,1024]

    char* ws = (char*)d_ws;
    unsigned int* flags = (unsigned int*)(ws + 0);            // 4 groups x 16 flags @ 256B stride
    short* hb0    = (short*)(ws + 4096);                      // 128 KB
    short* hb1    = (short*)(ws + 4096 + 131072);             // 128 KB
    short* wih_bf = (short*)(ws + 266240);                    // 1 MB
    short* whh_bf = (short*)(ws + 1314816);                   // 2 MB

    // Zero flags + h0 buffers (ws is re-poisoned to 0xAA before every timed call).
    hipMemsetAsync(d_ws, 0, 266240, stream);

    cvt_kernel<<<512, 256, 0, stream>>>(wih, wih_bf, HID * INDIM);
    cvt_kernel<<<1024, 256, 0, stream>>>(whh, whh_bf, HID * HID);

    proj_kernel<<<16384, 256, 0, stream>>>(x, wih_bf, b_ih, b_hh, out);

    void* args[] = { (void*)&out, (void*)&whh_bf, (void*)&hb0, (void*)&hb1, (void*)&flags };
    hipLaunchCooperativeKernel((const void*)rnn_scan_kernel, dim3(64), dim3(256),
                               args, 0, stream);
}

// Round 5
// 5085.673 us; speedup vs baseline: 1.1441x; 1.0355x over previous
//
#include <hip/hip_runtime.h>
#include <hip/hip_bf16.h>

#define SEQ   1024
#define BATCH 64
#define INDIM 512
#define HID   1024

typedef __attribute__((ext_vector_type(8))) short bf16x8;
typedef __attribute__((ext_vector_type(4))) float f32x4;
typedef __attribute__((ext_vector_type(4))) int   i32x4;

// fp32 -> bf16 round-to-nearest-even
static __device__ __forceinline__ short f2bf(float f) {
    union { float f; unsigned u; } v; v.f = f;
    unsigned u = v.u;
    unsigned r = u + 0x7fffu + ((u >> 16) & 1u);
    return (short)(r >> 16);
}

// 16B device-coherent load: bypass L1 + XCD L2, read at the MALL coherence point.
static __device__ __forceinline__ i32x4 load16_coherent(const void* p) {
    i32x4 r;
    asm volatile("global_load_dwordx4 %0, %1, off sc0 sc1" : "=v"(r) : "v"(p) : "memory");
    return r;
}

// Division-free tanh via v_exp_f32 + v_rcp_f32; clamp +-9 avoids inf*0 NaN.
// (Validated: round-1 kernel passed with this, absmax 7.8e-3.)
static __device__ __forceinline__ float fast_tanh(float x) {
    x = fminf(9.0f, fmaxf(-9.0f, x));
    float e = __builtin_amdgcn_exp2f(2.8853900817779268f * x);   // e^{2x}
    return (e - 1.0f) * __builtin_amdgcn_rcpf(e + 1.0f);
}

__global__ __launch_bounds__(256) void cvt_kernel(const float* __restrict__ src,
                                                  short* __restrict__ dst, int n) {
    int i = blockIdx.x * blockDim.x + threadIdx.x;
    int stride = gridDim.x * blockDim.x;
    for (; i < n; i += stride) dst[i] = f2bf(src[i]);
}

// Phase A (round-1 proven, verbatim): fp32-A fallback variant.
__global__ __launch_bounds__(256) void proj_kernel(
    const float* __restrict__ x,      // [65536, 512] fp32
    const short* __restrict__ wih,    // [1024, 512] bf16
    const float* __restrict__ b_ih,
    const float* __restrict__ b_hh,
    float* __restrict__ out)          // [65536, 1024] fp32
{
    const int tid  = threadIdx.x;
    const int lane = tid & 63;
    const int w    = tid >> 6;
    const int wm   = w & 1, wn = w >> 1;
    const int l15  = lane & 15;
    const int quad = lane >> 4;

    const int id  = blockIdx.x;
    const int xcd = id & 7;
    const int q   = id >> 3;
    const int n   = q & 15;              // col panel 0..15
    const int p   = (q >> 4) * 8 + xcd;  // row panel 0..1023

    const int bm = p * 64 + wm * 32;
    const int bn = n * 64 + wn * 32;

    f32x4 acc[2][2] = {};

    for (int kk = 0; kk < INDIM; kk += 32) {
        const int kbase = kk + quad * 8;
        bf16x8 a[2], b[2];
#pragma unroll
        for (int mi = 0; mi < 2; ++mi) {
            const float* ap = x + (size_t)(bm + mi * 16 + l15) * INDIM + kbase;
            float4 lo = *reinterpret_cast<const float4*>(ap);
            float4 hi = *reinterpret_cast<const float4*>(ap + 4);
            bf16x8 af;
            af[0] = f2bf(lo.x); af[1] = f2bf(lo.y); af[2] = f2bf(lo.z); af[3] = f2bf(lo.w);
            af[4] = f2bf(hi.x); af[5] = f2bf(hi.y); af[6] = f2bf(hi.z); af[7] = f2bf(hi.w);
            a[mi] = af;
        }
#pragma unroll
        for (int ni = 0; ni < 2; ++ni)
            b[ni] = *reinterpret_cast<const bf16x8*>(wih + (size_t)(bn + ni * 16 + l15) * INDIM + kbase);
#pragma unroll
        for (int mi = 0; mi < 2; ++mi)
#pragma unroll
            for (int ni = 0; ni < 2; ++ni)
                acc[mi][ni] = __builtin_amdgcn_mfma_f32_16x16x32_bf16(a[mi], b[ni], acc[mi][ni], 0, 0, 0);
    }

#pragma unroll
    for (int mi = 0; mi < 2; ++mi) {
#pragma unroll
        for (int ni = 0; ni < 2; ++ni) {
            const int col = bn + ni * 16 + l15;
            const float bias = b_ih[col] + b_hh[col];
#pragma unroll
            for (int reg = 0; reg < 4; ++reg) {
                const int row = bm + mi * 16 + quad * 4 + reg;
                out[(size_t)row * HID + col] = acc[mi][ni][reg] + bias;
            }
        }
    }
}

// Phase A, bf16-A variant: x pre-converted to bf16 by cvt_kernel. Removes the
// 16x-redundant in-loop f2bf of every A panel (~256 f2bf VALU ops/thread, the
// dominant proj cost vs ~64 MFMA) and halves A read bytes. Numerics identical
// (same f2bf rounding, applied once instead of per-tile).
__global__ __launch_bounds__(256) void proj_kernel_bf(
    const short* __restrict__ xbf,    // [65536, 512] bf16
    const short* __restrict__ wih,    // [1024, 512] bf16
    const float* __restrict__ b_ih,
    const float* __restrict__ b_hh,
    float* __restrict__ out)          // [65536, 1024] fp32
{
    const int tid  = threadIdx.x;
    const int lane = tid & 63;
    const int w    = tid >> 6;
    const int wm   = w & 1, wn = w >> 1;
    const int l15  = lane & 15;
    const int quad = lane >> 4;

    const int id  = blockIdx.x;
    const int xcd = id & 7;
    const int q   = id >> 3;
    const int n   = q & 15;              // col panel 0..15
    const int p   = (q >> 4) * 8 + xcd;  // row panel 0..1023

    const int bm = p * 64 + wm * 32;
    const int bn = n * 64 + wn * 32;

    f32x4 acc[2][2] = {};

    for (int kk = 0; kk < INDIM; kk += 32) {
        const int kbase = kk + quad * 8;
        bf16x8 a[2], b[2];
#pragma unroll
        for (int mi = 0; mi < 2; ++mi)
            a[mi] = *reinterpret_cast<const bf16x8*>(xbf + (size_t)(bm + mi * 16 + l15) * INDIM + kbase);
#pragma unroll
        for (int ni = 0; ni < 2; ++ni)
            b[ni] = *reinterpret_cast<const bf16x8*>(wih + (size_t)(bn + ni * 16 + l15) * INDIM + kbase);
#pragma unroll
        for (int mi = 0; mi < 2; ++mi)
#pragma unroll
            for (int ni = 0; ni < 2; ++ni)
                acc[mi][ni] = __builtin_amdgcn_mfma_f32_16x16x32_bf16(a[mi], b[ni], acc[mi][ni], 0, 0, 0);
    }

#pragma unroll
    for (int mi = 0; mi < 2; ++mi) {
#pragma unroll
        for (int ni = 0; ni < 2; ++ni) {
            const int col = bn + ni * 16 + l15;
            const float bias = b_ih[col] + b_hh[col];
#pragma unroll
            for (int reg = 0; reg < 4; ++reg) {
                const int row = bm + mi * 16 + quad * 4 + reg;
                out[(size_t)row * HID + col] = acc[mi][ni][reg] + bias;
            }
        }
    }
}

// Phase B: cooperative scan — BYTE-EXACT round-1 source (the verified pass:
// 4265us, absmax 7.8e-3). No changes whatsoever this round; rounds 2-4 each
// perturbed this kernel and failed, so it is re-anchored verbatim.
__global__ __launch_bounds__(256) void rnn_scan_kernel(
    float* __restrict__ out,              // [SEQ,BATCH,HID]: holds xp, overwritten with h_t
    const short* __restrict__ whh,        // [1024,1024] bf16
    short* __restrict__ hb0,              // [BATCH,HID] bf16 (zeroed = h0)
    short* __restrict__ hb1,              // [BATCH,HID] bf16
    unsigned int* __restrict__ flags)     // 4 groups x 16 flags, 256B apart, zeroed
{
    const int tid  = threadIdx.x;
    const int lane = tid & 63;
    const int w    = tid >> 6;
    const int l15  = lane & 15;
    const int quad = lane >> 4;

    const int gid = blockIdx.x;   // 0..63
    const int g   = gid >> 4;     // group 0..3
    const int r   = gid & 15;     // col-block 0..15
    const int b0  = g * 16;       // first batch of group
    const int n0  = r * 64;       // first hidden col of block

    // Preload W_hh fragments (loop-invariant): n-tile nt covers cols n0+16nt+l15,
    // wave w covers k in [256w, 256w+256).
    bf16x8 wfrag[4][8];
#pragma unroll
    for (int nt = 0; nt < 4; ++nt)
#pragma unroll
        for (int ks = 0; ks < 8; ++ks) {
            const int k = 256 * w + ks * 32 + quad * 8;
            wfrag[nt][ks] = *reinterpret_cast<const bf16x8*>(
                whh + (size_t)(n0 + nt * 16 + l15) * HID + k);
        }

    __shared__ float red[4 * 1024];

    short* hbufs[2] = { hb0, hb1 };
    unsigned int* gflags = flags + g * 64;          // 256B stride per group
    const unsigned int* wflag = gflags + w * 4;     // this wave's 4 producers (16B)

    const int m  = tid >> 4;        // batch row within group
    const int c0 = (tid & 15) * 4;  // 4 consecutive cols per thread in epilogue

    for (int t = 0; t < SEQ; ++t) {
        const short* hc = hbufs[t & 1];
        short*       hn = hbufs[(t + 1) & 1];

        // Block-local xp prefetch (independent of the handshake).
        const size_t oidx = (size_t)t * (BATCH * HID) + (size_t)(b0 + m) * HID + n0 + c0;
        float4 xp = *reinterpret_cast<const float4*>(out + oidx);

        // Per-wave readiness: wait until our 4 K-quarter producers published h_t.
        if (t != 0) {
            const unsigned tgt = (unsigned)t;
            for (;;) {
                i32x4 fl;
                asm volatile("global_load_dwordx4 %0, %1, off sc0 sc1\n\ts_waitcnt vmcnt(0)"
                             : "=v"(fl) : "v"(wflag) : "memory");
                if ((unsigned)fl[0] >= tgt && (unsigned)fl[1] >= tgt &&
                    (unsigned)fl[2] >= tgt && (unsigned)fl[3] >= tgt) break;
            }
        }

        // Coherent h loads: row b0+l15, wave-w K-quarter (8 x 16B, pipelined).
        i32x4 araw[8];
        const short* abase = hc + (size_t)(b0 + l15) * HID + 256 * w + quad * 8;
#pragma unroll
        for (int ks = 0; ks < 8; ++ks)
            araw[ks] = load16_coherent(abase + ks * 32);

        f32x4 acc[4] = {};
        // Split wait: start MFMA on the first 4 returns while 4..7 are in flight.
        asm volatile("s_waitcnt vmcnt(4)"
            : "+v"(araw[0]), "+v"(araw[1]), "+v"(araw[2]), "+v"(araw[3]) :: "memory");
#pragma unroll
        for (int ks = 0; ks < 4; ++ks) {
            bf16x8 a = __builtin_bit_cast(bf16x8, araw[ks]);
#pragma unroll
            for (int nt = 0; nt < 4; ++nt)
                acc[nt] = __builtin_amdgcn_mfma_f32_16x16x32_bf16(a, wfrag[nt][ks], acc[nt], 0, 0, 0);
        }
        asm volatile("s_waitcnt vmcnt(0)"
            : "+v"(araw[4]), "+v"(araw[5]), "+v"(araw[6]), "+v"(araw[7]) :: "memory");
#pragma unroll
        for (int ks = 4; ks < 8; ++ks) {
            bf16x8 a = __builtin_bit_cast(bf16x8, araw[ks]);
#pragma unroll
            for (int nt = 0; nt < 4; ++nt)
                acc[nt] = __builtin_amdgcn_mfma_f32_16x16x32_bf16(a, wfrag[nt][ks], acc[nt], 0, 0, 0);
        }

        // Cross-wave K-reduction via LDS. C/D layout: col=l15, row=quad*4+reg.
#pragma unroll
        for (int nt = 0; nt < 4; ++nt)
#pragma unroll
            for (int reg = 0; reg < 4; ++reg)
                red[w * 1024 + (quad * 4 + reg) * 64 + nt * 16 + l15] = acc[nt][reg];
        __syncthreads();

        {
            // ds_read_b128 per partial (c0 is 16B-aligned).
            f32x4 s = *reinterpret_cast<const f32x4*>(&red[0 * 1024 + m * 64 + c0]);
#pragma unroll
            for (int wk = 1; wk < 4; ++wk) {
                f32x4 sp = *reinterpret_cast<const f32x4*>(&red[wk * 1024 + m * 64 + c0]);
                s[0] += sp[0]; s[1] += sp[1]; s[2] += sp[2]; s[3] += sp[3];
            }

            float v0 = fast_tanh(s[0] + xp.x);
            float v1 = fast_tanh(s[1] + xp.y);
            float v2 = fast_tanh(s[2] + xp.z);
            float v3 = fast_tanh(s[3] + xp.w);
            *reinterpret_cast<float4*>(out + oidx) = make_float4(v0, v1, v2, v3);

            // Device-scope h store: 4 bf16 packed into one 8B relaxed atomic (sc1).
            unsigned lo = (unsigned)(unsigned short)f2bf(v0) | ((unsigned)(unsigned short)f2bf(v1) << 16);
            unsigned hi = (unsigned)(unsigned short)f2bf(v2) | ((unsigned)(unsigned short)f2bf(v3) << 16);
            unsigned long long pk = (unsigned long long)lo | ((unsigned long long)hi << 32);
            __hip_atomic_store(
                reinterpret_cast<unsigned long long*>(hn + (size_t)(b0 + m) * HID + n0 + c0),
                pk, __ATOMIC_RELAXED, __HIP_MEMORY_SCOPE_AGENT);
        }

        // __syncthreads drains every thread's stores to (at least) the L2 port;
        // the release fence (buffer_wbl2 sc1) then drains the XCD L2 write path
        // to the MALL before the flag becomes visible.
        __syncthreads();
        if (tid == 0) {
            __builtin_amdgcn_fence(__ATOMIC_RELEASE, "agent");
            __hip_atomic_store(&gflags[r], (unsigned)(t + 1),
                               __ATOMIC_RELAXED, __HIP_MEMORY_SCOPE_AGENT);
        }
    }
}

extern "C" void kernel_launch(void* const* d_in, const int* in_sizes, int n_in,
                              void* d_out, int out_size, void* d_ws, size_t ws_size,
                              hipStream_t stream) {
    const float* x    = (const float*)d_in[0];   // [1024,64,512]
    const float* wih  = (const float*)d_in[1];   // [1024,512]
    const float* whh  = (const float*)d_in[2];   // [1024,1024]
    const float* b_ih = (const float*)d_in[3];   // [1024]
    const float* b_hh = (const float*)d_in[4];   // [1024]
    float* out = (float*)d_out;                  // [1024,64,1024]

    char* ws = (char*)d_ws;
    unsigned int* flags = (unsigned int*)(ws + 0);            // 4 groups x 16 flags @ 256B stride
    short* hb0    = (short*)(ws + 4096);                      // 128 KB
    short* hb1    = (short*)(ws + 4096 + 131072);             // 128 KB
    short* wih_bf = (short*)(ws + 266240);                    // 1 MB
    short* whh_bf = (short*)(ws + 1314816);                   // 2 MB
    short* x_bf   = (short*)(ws + 3411968);                   // 64 MB (optional)
    const size_t ws_needed_xbf = 3411968ull + (size_t)SEQ * BATCH * INDIM * 2;

    // Zero flags + h0 buffers (ws is re-poisoned to 0xAA before every timed call).
    hipMemsetAsync(d_ws, 0, 266240, stream);

    cvt_kernel<<<512, 256, 0, stream>>>(wih, wih_bf, HID * INDIM);
    cvt_kernel<<<1024, 256, 0, stream>>>(whh, whh_bf, HID * HID);

    if (ws_size >= ws_needed_xbf) {
        cvt_kernel<<<2048, 256, 0, stream>>>(x, x_bf, SEQ * BATCH * INDIM);
        proj_kernel_bf<<<16384, 256, 0, stream>>>(x_bf, wih_bf, b_ih, b_hh, out);
    } else {
        proj_kernel<<<16384, 256, 0, stream>>>(x, wih_bf, b_ih, b_hh, out);
    }

    void* args[] = { (void*)&out, (void*)&whh_bf, (void*)&hb0, (void*)&hb1, (void*)&flags };
    hipLaunchCooperativeKernel((const void*)rnn_scan_kernel, dim3(64), dim3(256),
                               args, 0, stream);
}

// Round 6
// 4853.671 us; speedup vs baseline: 1.1988x; 1.0478x over previous
//
#include <hip/hip_runtime.h>
#include <hip/hip_bf16.h>

#define SEQ   1024
#define BATCH 64
#define INDIM 512
#define HID   1024

typedef __attribute__((ext_vector_type(8))) short bf16x8;
typedef __attribute__((ext_vector_type(4))) float f32x4;
typedef __attribute__((ext_vector_type(4))) int   i32x4;

// fp32 -> bf16 round-to-nearest-even
static __device__ __forceinline__ short f2bf(float f) {
    union { float f; unsigned u; } v; v.f = f;
    unsigned u = v.u;
    unsigned r = u + 0x7fffu + ((u >> 16) & 1u);
    return (short)(r >> 16);
}

// 16B device-coherent load: bypass L1 + XCD L2, read at the MALL coherence point.
static __device__ __forceinline__ i32x4 load16_coherent(const void* p) {
    i32x4 r;
    asm volatile("global_load_dwordx4 %0, %1, off sc0 sc1" : "=v"(r) : "v"(p) : "memory");
    return r;
}

// Division-free tanh via v_exp_f32 + v_rcp_f32; clamp +-9 avoids inf*0 NaN.
// (Validated: rounds 1/5 passed with this, absmax 7.8e-3.)
static __device__ __forceinline__ float fast_tanh(float x) {
    x = fminf(9.0f, fmaxf(-9.0f, x));
    float e = __builtin_amdgcn_exp2f(2.8853900817779268f * x);   // e^{2x}
    return (e - 1.0f) * __builtin_amdgcn_rcpf(e + 1.0f);
}

// Vectorized fp32 -> bf16: 8 elems/iter (2x float4 in, one 16B store out).
// n8 = n/8. Replaces the scalar cvt (G13: scalar bf16 ~2x slower).
__global__ __launch_bounds__(256) void cvt8_kernel(const float* __restrict__ src,
                                                   short* __restrict__ dst, int n8) {
    int i = blockIdx.x * blockDim.x + threadIdx.x;
    int stride = gridDim.x * blockDim.x;
    for (; i < n8; i += stride) {
        const float* s = src + (size_t)i * 8;
        float4 lo = *reinterpret_cast<const float4*>(s);
        float4 hi = *reinterpret_cast<const float4*>(s + 4);
        bf16x8 v;
        v[0] = f2bf(lo.x); v[1] = f2bf(lo.y); v[2] = f2bf(lo.z); v[3] = f2bf(lo.w);
        v[4] = f2bf(hi.x); v[5] = f2bf(hi.y); v[6] = f2bf(hi.z); v[7] = f2bf(hi.w);
        *reinterpret_cast<bf16x8*>(dst + (size_t)i * 8) = v;
    }
}

// Phase A fallback (round-1 proven, verbatim): fp32-A, 64x64 tile. Used only
// if the workspace can't hold x_bf.
__global__ __launch_bounds__(256) void proj_kernel(
    const float* __restrict__ x,      // [65536, 512] fp32
    const short* __restrict__ wih,    // [1024, 512] bf16
    const float* __restrict__ b_ih,
    const float* __restrict__ b_hh,
    float* __restrict__ out)          // [65536, 1024] fp32
{
    const int tid  = threadIdx.x;
    const int lane = tid & 63;
    const int w    = tid >> 6;
    const int wm   = w & 1, wn = w >> 1;
    const int l15  = lane & 15;
    const int quad = lane >> 4;

    const int id  = blockIdx.x;
    const int xcd = id & 7;
    const int q   = id >> 3;
    const int n   = q & 15;              // col panel 0..15
    const int p   = (q >> 4) * 8 + xcd;  // row panel 0..1023

    const int bm = p * 64 + wm * 32;
    const int bn = n * 64 + wn * 32;

    f32x4 acc[2][2] = {};

    for (int kk = 0; kk < INDIM; kk += 32) {
        const int kbase = kk + quad * 8;
        bf16x8 a[2], b[2];
#pragma unroll
        for (int mi = 0; mi < 2; ++mi) {
            const float* ap = x + (size_t)(bm + mi * 16 + l15) * INDIM + kbase;
            float4 lo = *reinterpret_cast<const float4*>(ap);
            float4 hi = *reinterpret_cast<const float4*>(ap + 4);
            bf16x8 af;
            af[0] = f2bf(lo.x); af[1] = f2bf(lo.y); af[2] = f2bf(lo.z); af[3] = f2bf(lo.w);
            af[4] = f2bf(hi.x); af[5] = f2bf(hi.y); af[6] = f2bf(hi.z); af[7] = f2bf(hi.w);
            a[mi] = af;
        }
#pragma unroll
        for (int ni = 0; ni < 2; ++ni)
            b[ni] = *reinterpret_cast<const bf16x8*>(wih + (size_t)(bn + ni * 16 + l15) * INDIM + kbase);
#pragma unroll
        for (int mi = 0; mi < 2; ++mi)
#pragma unroll
            for (int ni = 0; ni < 2; ++ni)
                acc[mi][ni] = __builtin_amdgcn_mfma_f32_16x16x32_bf16(a[mi], b[ni], acc[mi][ni], 0, 0, 0);
    }

#pragma unroll
    for (int mi = 0; mi < 2; ++mi) {
#pragma unroll
        for (int ni = 0; ni < 2; ++ni) {
            const int col = bn + ni * 16 + l15;
            const float bias = b_ih[col] + b_hh[col];
#pragma unroll
            for (int reg = 0; reg < 4; ++reg) {
                const int row = bm + mi * 16 + quad * 4 + reg;
                out[(size_t)row * HID + col] = acc[mi][ni][reg] + bias;
            }
        }
    }
}

// Phase A, 128x128-tile bf16 variant: 4 waves in 2x2, each wave owns a 64x64
// sub-tile (4x4 fragments of 16x16). Per k-step: 8 global loads feed 16 MFMAs
// (vs 4:4 in the 64x64 version) — fixes the MFMA:VMEM starvation that left the
// old proj at ~100 TF. Grid 4096, XCD-chunked: the 8 col-panel blocks sharing
// one 128-row A panel (128 KB bf16) sit on the same XCD within a 64-id window
// -> A served from that XCD's L2 after one HBM fetch; B (1 MB total) is
// L2-resident everywhere. Numerics identical to proj_kernel (same f2bf, same
// MFMA order per output element: K ascending in steps of 32).
__global__ __launch_bounds__(256) void proj_kernel_bf2(
    const short* __restrict__ xbf,    // [65536, 512] bf16
    const short* __restrict__ wih,    // [1024, 512] bf16
    const float* __restrict__ b_ih,
    const float* __restrict__ b_hh,
    float* __restrict__ out)          // [65536, 1024] fp32
{
    const int tid  = threadIdx.x;
    const int lane = tid & 63;
    const int w    = tid >> 6;
    const int wm   = w & 1, wn = w >> 1;
    const int l15  = lane & 15;
    const int quad = lane >> 4;

    const int id  = blockIdx.x;          // 0..4095
    const int xcd = id & 7;
    const int q   = id >> 3;
    const int n   = q & 7;               // col panel 0..7   (128 cols)
    const int p   = (q >> 3) * 8 + xcd;  // row panel 0..511 (128 rows)

    const int bm = p * 128 + wm * 64;
    const int bn = n * 128 + wn * 64;

    f32x4 acc[4][4] = {};

    for (int kk = 0; kk < INDIM; kk += 32) {
        const int kbase = kk + quad * 8;
        bf16x8 a[4], b[4];
#pragma unroll
        for (int mi = 0; mi < 4; ++mi)
            a[mi] = *reinterpret_cast<const bf16x8*>(xbf + (size_t)(bm + mi * 16 + l15) * INDIM + kbase);
#pragma unroll
        for (int ni = 0; ni < 4; ++ni)
            b[ni] = *reinterpret_cast<const bf16x8*>(wih + (size_t)(bn + ni * 16 + l15) * INDIM + kbase);
#pragma unroll
        for (int mi = 0; mi < 4; ++mi)
#pragma unroll
            for (int ni = 0; ni < 4; ++ni)
                acc[mi][ni] = __builtin_amdgcn_mfma_f32_16x16x32_bf16(a[mi], b[ni], acc[mi][ni], 0, 0, 0);
    }

#pragma unroll
    for (int mi = 0; mi < 4; ++mi) {
#pragma unroll
        for (int ni = 0; ni < 4; ++ni) {
            const int col = bn + ni * 16 + l15;
            const float bias = b_ih[col] + b_hh[col];
#pragma unroll
            for (int reg = 0; reg < 4; ++reg) {
                const int row = bm + mi * 16 + quad * 4 + reg;
                out[(size_t)row * HID + col] = acc[mi][ni][reg] + bias;
            }
        }
    }
}

// Phase B: cooperative scan — BYTE-EXACT round-1/round-5 source (verified pass:
// absmax 7.8e-3, 4189us). Frozen: rounds 2-4 each perturbed this kernel and
// failed; no scan edits this round (proj-only round per bisect discipline).
__global__ __launch_bounds__(256) void rnn_scan_kernel(
    float* __restrict__ out,              // [SEQ,BATCH,HID]: holds xp, overwritten with h_t
    const short* __restrict__ whh,        // [1024,1024] bf16
    short* __restrict__ hb0,              // [BATCH,HID] bf16 (zeroed = h0)
    short* __restrict__ hb1,              // [BATCH,HID] bf16
    unsigned int* __restrict__ flags)     // 4 groups x 16 flags, 256B apart, zeroed
{
    const int tid  = threadIdx.x;
    const int lane = tid & 63;
    const int w    = tid >> 6;
    const int l15  = lane & 15;
    const int quad = lane >> 4;

    const int gid = blockIdx.x;   // 0..63
    const int g   = gid >> 4;     // group 0..3
    const int r   = gid & 15;     // col-block 0..15
    const int b0  = g * 16;       // first batch of group
    const int n0  = r * 64;       // first hidden col of block

    // Preload W_hh fragments (loop-invariant): n-tile nt covers cols n0+16nt+l15,
    // wave w covers k in [256w, 256w+256).
    bf16x8 wfrag[4][8];
#pragma unroll
    for (int nt = 0; nt < 4; ++nt)
#pragma unroll
        for (int ks = 0; ks < 8; ++ks) {
            const int k = 256 * w + ks * 32 + quad * 8;
            wfrag[nt][ks] = *reinterpret_cast<const bf16x8*>(
                whh + (size_t)(n0 + nt * 16 + l15) * HID + k);
        }

    __shared__ float red[4 * 1024];

    short* hbufs[2] = { hb0, hb1 };
    unsigned int* gflags = flags + g * 64;          // 256B stride per group
    const unsigned int* wflag = gflags + w * 4;     // this wave's 4 producers (16B)

    const int m  = tid >> 4;        // batch row within group
    const int c0 = (tid & 15) * 4;  // 4 consecutive cols per thread in epilogue

    for (int t = 0; t < SEQ; ++t) {
        const short* hc = hbufs[t & 1];
        short*       hn = hbufs[(t + 1) & 1];

        // Block-local xp prefetch (independent of the handshake).
        const size_t oidx = (size_t)t * (BATCH * HID) + (size_t)(b0 + m) * HID + n0 + c0;
        float4 xp = *reinterpret_cast<const float4*>(out + oidx);

        // Per-wave readiness: wait until our 4 K-quarter producers published h_t.
        if (t != 0) {
            const unsigned tgt = (unsigned)t;
            for (;;) {
                i32x4 fl;
                asm volatile("global_load_dwordx4 %0, %1, off sc0 sc1\n\ts_waitcnt vmcnt(0)"
                             : "=v"(fl) : "v"(wflag) : "memory");
                if ((unsigned)fl[0] >= tgt && (unsigned)fl[1] >= tgt &&
                    (unsigned)fl[2] >= tgt && (unsigned)fl[3] >= tgt) break;
            }
        }

        // Coherent h loads: row b0+l15, wave-w K-quarter (8 x 16B, pipelined).
        i32x4 araw[8];
        const short* abase = hc + (size_t)(b0 + l15) * HID + 256 * w + quad * 8;
#pragma unroll
        for (int ks = 0; ks < 8; ++ks)
            araw[ks] = load16_coherent(abase + ks * 32);

        f32x4 acc[4] = {};
        // Split wait: start MFMA on the first 4 returns while 4..7 are in flight.
        asm volatile("s_waitcnt vmcnt(4)"
            : "+v"(araw[0]), "+v"(araw[1]), "+v"(araw[2]), "+v"(araw[3]) :: "memory");
#pragma unroll
        for (int ks = 0; ks < 4; ++ks) {
            bf16x8 a = __builtin_bit_cast(bf16x8, araw[ks]);
#pragma unroll
            for (int nt = 0; nt < 4; ++nt)
                acc[nt] = __builtin_amdgcn_mfma_f32_16x16x32_bf16(a, wfrag[nt][ks], acc[nt], 0, 0, 0);
        }
        asm volatile("s_waitcnt vmcnt(0)"
            : "+v"(araw[4]), "+v"(araw[5]), "+v"(araw[6]), "+v"(araw[7]) :: "memory");
#pragma unroll
        for (int ks = 4; ks < 8; ++ks) {
            bf16x8 a = __builtin_bit_cast(bf16x8, araw[ks]);
#pragma unroll
            for (int nt = 0; nt < 4; ++nt)
                acc[nt] = __builtin_amdgcn_mfma_f32_16x16x32_bf16(a, wfrag[nt][ks], acc[nt], 0, 0, 0);
        }

        // Cross-wave K-reduction via LDS. C/D layout: col=l15, row=quad*4+reg.
#pragma unroll
        for (int nt = 0; nt < 4; ++nt)
#pragma unroll
            for (int reg = 0; reg < 4; ++reg)
                red[w * 1024 + (quad * 4 + reg) * 64 + nt * 16 + l15] = acc[nt][reg];
        __syncthreads();

        {
            // ds_read_b128 per partial (c0 is 16B-aligned).
            f32x4 s = *reinterpret_cast<const f32x4*>(&red[0 * 1024 + m * 64 + c0]);
#pragma unroll
            for (int wk = 1; wk < 4; ++wk) {
                f32x4 sp = *reinterpret_cast<const f32x4*>(&red[wk * 1024 + m * 64 + c0]);
                s[0] += sp[0]; s[1] += sp[1]; s[2] += sp[2]; s[3] += sp[3];
            }

            float v0 = fast_tanh(s[0] + xp.x);
            float v1 = fast_tanh(s[1] + xp.y);
            float v2 = fast_tanh(s[2] + xp.z);
            float v3 = fast_tanh(s[3] + xp.w);
            *reinterpret_cast<float4*>(out + oidx) = make_float4(v0, v1, v2, v3);

            // Device-scope h store: 4 bf16 packed into one 8B relaxed atomic (sc1).
            unsigned lo = (unsigned)(unsigned short)f2bf(v0) | ((unsigned)(unsigned short)f2bf(v1) << 16);
            unsigned hi = (unsigned)(unsigned short)f2bf(v2) | ((unsigned)(unsigned short)f2bf(v3) << 16);
            unsigned long long pk = (unsigned long long)lo | ((unsigned long long)hi << 32);
            __hip_atomic_store(
                reinterpret_cast<unsigned long long*>(hn + (size_t)(b0 + m) * HID + n0 + c0),
                pk, __ATOMIC_RELAXED, __HIP_MEMORY_SCOPE_AGENT);
        }

        // __syncthreads drains every thread's stores to (at least) the L2 port;
        // the release fence (buffer_wbl2 sc1) then drains the XCD L2 write path
        // to the MALL before the flag becomes visible.
        __syncthreads();
        if (tid == 0) {
            __builtin_amdgcn_fence(__ATOMIC_RELEASE, "agent");
            __hip_atomic_store(&gflags[r], (unsigned)(t + 1),
                               __ATOMIC_RELAXED, __HIP_MEMORY_SCOPE_AGENT);
        }
    }
}

extern "C" void kernel_launch(void* const* d_in, const int* in_sizes, int n_in,
                              void* d_out, int out_size, void* d_ws, size_t ws_size,
                              hipStream_t stream) {
    const float* x    = (const float*)d_in[0];   // [1024,64,512]
    const float* wih  = (const float*)d_in[1];   // [1024,512]
    const float* whh  = (const float*)d_in[2];   // [1024,1024]
    const float* b_ih = (const float*)d_in[3];   // [1024]
    const float* b_hh = (const float*)d_in[4];   // [1024]
    float* out = (float*)d_out;                  // [1024,64,1024]

    char* ws = (char*)d_ws;
    unsigned int* flags = (unsigned int*)(ws + 0);            // 4 groups x 16 flags @ 256B stride
    short* hb0    = (short*)(ws + 4096);                      // 128 KB
    short* hb1    = (short*)(ws + 4096 + 131072);             // 128 KB
    short* wih_bf = (short*)(ws + 266240);                    // 1 MB
    short* whh_bf = (short*)(ws + 1314816);                   // 2 MB
    short* x_bf   = (short*)(ws + 3411968);                   // 64 MB (optional)
    const size_t ws_needed_xbf = 3411968ull + (size_t)SEQ * BATCH * INDIM * 2;

    // Zero flags + h0 buffers (ws is re-poisoned to 0xAA before every timed call).
    hipMemsetAsync(d_ws, 0, 266240, stream);

    cvt8_kernel<<<256, 256, 0, stream>>>(wih, wih_bf, HID * INDIM / 8);
    cvt8_kernel<<<512, 256, 0, stream>>>(whh, whh_bf, HID * HID / 8);

    if (ws_size >= ws_needed_xbf) {
        cvt8_kernel<<<2048, 256, 0, stream>>>(x, x_bf, SEQ * BATCH * INDIM / 8);
        proj_kernel_bf2<<<4096, 256, 0, stream>>>(x_bf, wih_bf, b_ih, b_hh, out);
    } else {
        proj_kernel<<<16384, 256, 0, stream>>>(x, wih_bf, b_ih, b_hh, out);
    }

    void* args[] = { (void*)&out, (void*)&whh_bf, (void*)&hb0, (void*)&hb1, (void*)&flags };
    hipLaunchCooperativeKernel((const void*)rnn_scan_kernel, dim3(64), dim3(256),
                               args, 0, stream);
}

// Round 7
// 4343.304 us; speedup vs baseline: 1.3397x; 1.1175x over previous
//
#include <hip/hip_runtime.h>
#include <hip/hip_bf16.h>

#define SEQ   1024
#define BATCH 64
#define INDIM 512
#define HID   1024

typedef __attribute__((ext_vector_type(8))) short bf16x8;
typedef __attribute__((ext_vector_type(4))) float f32x4;
typedef __attribute__((ext_vector_type(4))) int   i32x4;

// fp32 -> bf16 round-to-nearest-even
static __device__ __forceinline__ short f2bf(float f) {
    union { float f; unsigned u; } v; v.f = f;
    unsigned u = v.u;
    unsigned r = u + 0x7fffu + ((u >> 16) & 1u);
    return (short)(r >> 16);
}

// Division-free tanh via v_exp_f32 + v_rcp_f32; clamp +-9 avoids inf*0 NaN.
// (Validated: rounds 1/5/6 passed with this, absmax 7.8e-3.)
static __device__ __forceinline__ float fast_tanh(float x) {
    x = fminf(9.0f, fmaxf(-9.0f, x));
    float e = __builtin_amdgcn_exp2f(2.8853900817779268f * x);   // e^{2x}
    return (e - 1.0f) * __builtin_amdgcn_rcpf(e + 1.0f);
}

// Vectorized fp32 -> bf16: 8 elems/iter (2x float4 in, one 16B store out).
__global__ __launch_bounds__(256) void cvt8_kernel(const float* __restrict__ src,
                                                   short* __restrict__ dst, int n8) {
    int i = blockIdx.x * blockDim.x + threadIdx.x;
    int stride = gridDim.x * blockDim.x;
    for (; i < n8; i += stride) {
        const float* s = src + (size_t)i * 8;
        float4 lo = *reinterpret_cast<const float4*>(s);
        float4 hi = *reinterpret_cast<const float4*>(s + 4);
        bf16x8 v;
        v[0] = f2bf(lo.x); v[1] = f2bf(lo.y); v[2] = f2bf(lo.z); v[3] = f2bf(lo.w);
        v[4] = f2bf(hi.x); v[5] = f2bf(hi.y); v[6] = f2bf(hi.z); v[7] = f2bf(hi.w);
        *reinterpret_cast<bf16x8*>(dst + (size_t)i * 8) = v;
    }
}

// Phase A fallback (round-1 proven, verbatim): fp32-A, 64x64 tile.
__global__ __launch_bounds__(256) void proj_kernel(
    const float* __restrict__ x,
    const short* __restrict__ wih,
    const float* __restrict__ b_ih,
    const float* __restrict__ b_hh,
    float* __restrict__ out)
{
    const int tid  = threadIdx.x;
    const int lane = tid & 63;
    const int w    = tid >> 6;
    const int wm   = w & 1, wn = w >> 1;
    const int l15  = lane & 15;
    const int quad = lane >> 4;

    const int id  = blockIdx.x;
    const int xcd = id & 7;
    const int q   = id >> 3;
    const int n   = q & 15;
    const int p   = (q >> 4) * 8 + xcd;

    const int bm = p * 64 + wm * 32;
    const int bn = n * 64 + wn * 32;

    f32x4 acc[2][2] = {};

    for (int kk = 0; kk < INDIM; kk += 32) {
        const int kbase = kk + quad * 8;
        bf16x8 a[2], b[2];
#pragma unroll
        for (int mi = 0; mi < 2; ++mi) {
            const float* ap = x + (size_t)(bm + mi * 16 + l15) * INDIM + kbase;
            float4 lo = *reinterpret_cast<const float4*>(ap);
            float4 hi = *reinterpret_cast<const float4*>(ap + 4);
            bf16x8 af;
            af[0] = f2bf(lo.x); af[1] = f2bf(lo.y); af[2] = f2bf(lo.z); af[3] = f2bf(lo.w);
            af[4] = f2bf(hi.x); af[5] = f2bf(hi.y); af[6] = f2bf(hi.z); af[7] = f2bf(hi.w);
            a[mi] = af;
        }
#pragma unroll
        for (int ni = 0; ni < 2; ++ni)
            b[ni] = *reinterpret_cast<const bf16x8*>(wih + (size_t)(bn + ni * 16 + l15) * INDIM + kbase);
#pragma unroll
        for (int mi = 0; mi < 2; ++mi)
#pragma unroll
            for (int ni = 0; ni < 2; ++ni)
                acc[mi][ni] = __builtin_amdgcn_mfma_f32_16x16x32_bf16(a[mi], b[ni], acc[mi][ni], 0, 0, 0);
    }

#pragma unroll
    for (int mi = 0; mi < 2; ++mi) {
#pragma unroll
        for (int ni = 0; ni < 2; ++ni) {
            const int col = bn + ni * 16 + l15;
            const float bias = b_ih[col] + b_hh[col];
#pragma unroll
            for (int reg = 0; reg < 4; ++reg) {
                const int row = bm + mi * 16 + quad * 4 + reg;
                out[(size_t)row * HID + col] = acc[mi][ni][reg] + bias;
            }
        }
    }
}

// Phase A, 128x128-tile bf16 variant (round-6 proven, verbatim).
__global__ __launch_bounds__(256) void proj_kernel_bf2(
    const short* __restrict__ xbf,
    const short* __restrict__ wih,
    const float* __restrict__ b_ih,
    const float* __restrict__ b_hh,
    float* __restrict__ out)
{
    const int tid  = threadIdx.x;
    const int lane = tid & 63;
    const int w    = tid >> 6;
    const int wm   = w & 1, wn = w >> 1;
    const int l15  = lane & 15;
    const int quad = lane >> 4;

    const int id  = blockIdx.x;
    const int xcd = id & 7;
    const int q   = id >> 3;
    const int n   = q & 7;
    const int p   = (q >> 3) * 8 + xcd;

    const int bm = p * 128 + wm * 64;
    const int bn = n * 128 + wn * 64;

    f32x4 acc[4][4] = {};

    for (int kk = 0; kk < INDIM; kk += 32) {
        const int kbase = kk + quad * 8;
        bf16x8 a[4], b[4];
#pragma unroll
        for (int mi = 0; mi < 4; ++mi)
            a[mi] = *reinterpret_cast<const bf16x8*>(xbf + (size_t)(bm + mi * 16 + l15) * INDIM + kbase);
#pragma unroll
        for (int ni = 0; ni < 4; ++ni)
            b[ni] = *reinterpret_cast<const bf16x8*>(wih + (size_t)(bn + ni * 16 + l15) * INDIM + kbase);
#pragma unroll
        for (int mi = 0; mi < 4; ++mi)
#pragma unroll
            for (int ni = 0; ni < 4; ++ni)
                acc[mi][ni] = __builtin_amdgcn_mfma_f32_16x16x32_bf16(a[mi], b[ni], acc[mi][ni], 0, 0, 0);
    }

#pragma unroll
    for (int mi = 0; mi < 4; ++mi) {
#pragma unroll
        for (int ni = 0; ni < 4; ++ni) {
            const int col = bn + ni * 16 + l15;
            const float bias = b_ih[col] + b_hh[col];
#pragma unroll
            for (int reg = 0; reg < 4; ++reg) {
                const int row = bm + mi * 16 + quad * 4 + reg;
                out[(size_t)row * HID + col] = acc[mi][ni][reg] + bias;
            }
        }
    }
}

// Phase B: cooperative scan with TAG-EMBEDDED h publication.
// h buffer = [64 rows][256 slots] of 16B: {u32 tag, u32 pad, u32 h01, u32 h23}
// (4 bf16 h-values per slot). Producer publishes h+tag in ONE dwordx4 sc0sc1
// store; consumers poll their 16 slots directly (tag==t) — the poll IS the h
// load. Deletes: release fence (buffer_wbl2), flag store, end-of-step
// __syncthreads, and the separate h-load RT.
//
// Anti-overwrite induction (same as flag protocol): a thread stores tag t+1
// only after its block's mid-step barrier at t, which requires all 4 waves'
// polls to have seen tag t from all 16 blocks of the group; a block's tag-t
// slots are written by threads of ALL its waves (m=0..15 spans all 4), each
// past its own step-(t-1) epilogue => every wave's step-(t-1) reads (incl.
// LDS red reads) are complete before any tag t+1 overwrite. red is
// double-buffered so no trailing barrier is needed.
//
// Stale-tag safety across timed calls: buf0 is re-zeroed (tag 0 = t=0 expect,
// h0 = 0); buf1's stale tags (0xAA poison or prior-call 1023) are overwritten
// in sequence before any consumer can reach the step that expects them.
// Poll cap 8192 converts any deadlock into a finite wrong answer (no hang).
__global__ __launch_bounds__(256) void rnn_scan_tag_kernel(
    float* __restrict__ out,              // [SEQ,BATCH,HID]: holds xp, overwritten with h_t
    const short* __restrict__ whh,        // [1024,1024] bf16
    unsigned int* __restrict__ hbt0,      // [64][256] 16B slots, zeroed (= h0, tag 0)
    unsigned int* __restrict__ hbt1)      // [64][256] 16B slots (poison ok)
{
    const int tid  = threadIdx.x;
    const int lane = tid & 63;
    const int w    = tid >> 6;
    const int l15  = lane & 15;
    const int quad = lane >> 4;

    const int gid = blockIdx.x;   // 0..63
    const int g   = gid >> 4;     // group 0..3
    const int r   = gid & 15;     // col-block 0..15
    const int b0  = g * 16;       // first batch of group
    const int n0  = r * 64;       // first hidden col of block

    // Preload W_hh fragments (unchanged from the proven scan).
    bf16x8 wfrag[4][8];
#pragma unroll
    for (int nt = 0; nt < 4; ++nt)
#pragma unroll
        for (int ks = 0; ks < 8; ++ks) {
            const int k = 256 * w + ks * 32 + quad * 8;
            wfrag[nt][ks] = *reinterpret_cast<const bf16x8*>(
                whh + (size_t)(n0 + nt * 16 + l15) * HID + k);
        }

    __shared__ float red[2][4096];   // double-buffered: no end-of-step barrier

    unsigned int* hbufs[2] = { hbt0, hbt1 };

    const int m  = tid >> 4;        // batch row within group (epilogue)
    const int c0 = (tid & 15) * 4;  // 4 consecutive cols per thread (epilogue)

    for (int t = 0; t < SEQ; ++t) {
        const unsigned int* hc = hbufs[t & 1];
        unsigned int*       hn = hbufs[(t + 1) & 1];

        // xp prefetch (plain cached; drained by the poll's vmcnt(0), harmless).
        const size_t oidx = (size_t)t * (BATCH * HID) + (size_t)(b0 + m) * HID + n0 + c0;
        float4 xp = *reinterpret_cast<const float4*>(out + oidx);

        // Poll-and-load: wave w's 16 slots = rows b0+l15, slots 64w+8ks+2quad+{0,1}
        // (k-range [256w,256w+256)). Byte offsets from pb: 128*ks and 128*ks+16.
        const char* pb = (const char*)hc +
            (((size_t)(b0 + l15) * 256 + 64 * w + 2 * quad) << 4);
        i32x4 sl[16];
        int iter = 0;
        for (;;) {
#define PL(i, OFF) asm volatile("global_load_dwordx4 %0, %1, off offset:" OFF " sc0 sc1" \
                                : "=v"(sl[i]) : "v"(pb) : "memory")
            PL(0, "0");   PL(1, "16");  PL(2, "128"); PL(3, "144");
            PL(4, "256"); PL(5, "272"); PL(6, "384"); PL(7, "400");
            PL(8, "512"); PL(9, "528"); PL(10, "640"); PL(11, "656");
            PL(12, "768"); PL(13, "784"); PL(14, "896"); PL(15, "912");
#undef PL
            asm volatile("s_waitcnt vmcnt(0)"
                : "+v"(sl[0]), "+v"(sl[1]), "+v"(sl[2]), "+v"(sl[3]),
                  "+v"(sl[4]), "+v"(sl[5]), "+v"(sl[6]), "+v"(sl[7]),
                  "+v"(sl[8]), "+v"(sl[9]), "+v"(sl[10]), "+v"(sl[11]),
                  "+v"(sl[12]), "+v"(sl[13]), "+v"(sl[14]), "+v"(sl[15]) :: "memory");
            int ok = (sl[0][0] == t) & (sl[1][0] == t) & (sl[2][0] == t) & (sl[3][0] == t) &
                     (sl[4][0] == t) & (sl[5][0] == t) & (sl[6][0] == t) & (sl[7][0] == t) &
                     (sl[8][0] == t) & (sl[9][0] == t) & (sl[10][0] == t) & (sl[11][0] == t) &
                     (sl[12][0] == t) & (sl[13][0] == t) & (sl[14][0] == t) & (sl[15][0] == t);
            if (__all(ok)) break;
            if (++iter >= 8192) break;   // failsafe: wrong answer beats a hang
        }

        // h MFMAs — data already in registers (slot words 2,3 = 4 bf16 each).
        f32x4 acc[4] = {};
#pragma unroll
        for (int ks = 0; ks < 8; ++ks) {
            i32x4 aw;
            aw[0] = sl[2 * ks][2];     aw[1] = sl[2 * ks][3];
            aw[2] = sl[2 * ks + 1][2]; aw[3] = sl[2 * ks + 1][3];
            bf16x8 a = __builtin_bit_cast(bf16x8, aw);
#pragma unroll
            for (int nt = 0; nt < 4; ++nt)
                acc[nt] = __builtin_amdgcn_mfma_f32_16x16x32_bf16(a, wfrag[nt][ks], acc[nt], 0, 0, 0);
        }

        // Cross-wave K-reduction (double-buffered). C/D: col=l15, row=quad*4+reg.
        float* rw = &red[t & 1][0];
#pragma unroll
        for (int nt = 0; nt < 4; ++nt)
#pragma unroll
            for (int reg = 0; reg < 4; ++reg)
                rw[w * 1024 + (quad * 4 + reg) * 64 + nt * 16 + l15] = acc[nt][reg];
        __syncthreads();   // the ONLY barrier per step

        {
            f32x4 s = *reinterpret_cast<const f32x4*>(&rw[m * 64 + c0]);
#pragma unroll
            for (int wk = 1; wk < 4; ++wk) {
                f32x4 sp = *reinterpret_cast<const f32x4*>(&rw[wk * 1024 + m * 64 + c0]);
                s[0] += sp[0]; s[1] += sp[1]; s[2] += sp[2]; s[3] += sp[3];
            }

            float v0 = fast_tanh(s[0] + xp.x);
            float v1 = fast_tanh(s[1] + xp.y);
            float v2 = fast_tanh(s[2] + xp.z);
            float v3 = fast_tanh(s[3] + xp.w);
            *reinterpret_cast<float4*>(out + oidx) = make_float4(v0, v1, v2, v3);

            // Publish h_{t+1}: ONE 16B device-coherent store {tag, pad, h01, h23}.
            unsigned lo = (unsigned)(unsigned short)f2bf(v0) | ((unsigned)(unsigned short)f2bf(v1) << 16);
            unsigned hi = (unsigned)(unsigned short)f2bf(v2) | ((unsigned)(unsigned short)f2bf(v3) << 16);
            i32x4 st;
            st[0] = t + 1; st[1] = 0; st[2] = (int)lo; st[3] = (int)hi;
            unsigned int* dst = hn + (((size_t)(b0 + m) * 256 + r * 16 + (tid & 15)) << 2);
            asm volatile("global_store_dwordx4 %0, %1, off sc0 sc1"
                         :: "v"(dst), "v"(st) : "memory");
        }
        // No trailing barrier, no fence, no flag: next poll's vmcnt(0) drains
        // our stores in parallel with its own slot loads.
    }
}

extern "C" void kernel_launch(void* const* d_in, const int* in_sizes, int n_in,
                              void* d_out, int out_size, void* d_ws, size_t ws_size,
                              hipStream_t stream) {
    const float* x    = (const float*)d_in[0];   // [1024,64,512]
    const float* wih  = (const float*)d_in[1];   // [1024,512]
    const float* whh  = (const float*)d_in[2];   // [1024,1024]
    const float* b_ih = (const float*)d_in[3];   // [1024]
    const float* b_hh = (const float*)d_in[4];   // [1024]
    float* out = (float*)d_out;                  // [1024,64,1024]

    char* ws = (char*)d_ws;
    unsigned int* hbt0 = (unsigned int*)(ws + 0);             // 256 KB tag-slots (h even)
    unsigned int* hbt1 = (unsigned int*)(ws + 262144);        // 256 KB tag-slots (h odd)
    short* wih_bf = (short*)(ws + 524288);                    // 1 MB
    short* whh_bf = (short*)(ws + 1572864);                   // 2 MB
    short* x_bf   = (short*)(ws + 3670016);                   // 64 MB (optional)
    const size_t ws_needed_xbf = 3670016ull + (size_t)SEQ * BATCH * INDIM * 2;

    // Zero buf0 only: tag 0 == step-0 expectation, h0 = 0. buf1 stale tags are
    // provably overwritten before any consumer expects them.
    hipMemsetAsync(d_ws, 0, 262144, stream);

    cvt8_kernel<<<256, 256, 0, stream>>>(wih, wih_bf, HID * INDIM / 8);
    cvt8_kernel<<<512, 256, 0, stream>>>(whh, whh_bf, HID * HID / 8);

    if (ws_size >= ws_needed_xbf) {
        cvt8_kernel<<<2048, 256, 0, stream>>>(x, x_bf, SEQ * BATCH * INDIM / 8);
        proj_kernel_bf2<<<4096, 256, 0, stream>>>(x_bf, wih_bf, b_ih, b_hh, out);
    } else {
        proj_kernel<<<16384, 256, 0, stream>>>(x, wih_bf, b_ih, b_hh, out);
    }

    // Cooperative launch with error-checked fallback: rounds 2-4's bit-exact
    // "max|ref|" absmax indicates the cooperative launch silently failed and
    // the scan never ran. The protocol never required the cooperative API
    // (64 blocks at 1 block/CU are trivially co-resident on 256 CUs), so a
    // normal launch is a correct fallback.
    void* args[] = { (void*)&out, (void*)&whh_bf, (void*)&hbt0, (void*)&hbt1 };
    hipError_t e = hipLaunchCooperativeKernel((const void*)rnn_scan_tag_kernel,
                                              dim3(64), dim3(256), args, 0, stream);
    if (e != hipSuccess) {
        rnn_scan_tag_kernel<<<dim3(64), dim3(256), 0, stream>>>(out, whh_bf, hbt0, hbt1);
    }
}